// Round 3
// baseline (352.134 us; speedup 1.0000x reference)
//
#include <hip/hip_runtime.h>
#include <hip/hip_bf16.h>

#define N_SITES 50000
#define N_PERM  12
#define N_NEIGH 8
#define NODE_F  64
#define IN_F    512
#define OUT_F   64
#define N_TILES (N_SITES / 16)   // 3125 exact, one block per tile
#define LN2F    0.69314718055994530942f

#define XCHUNKS (N_SITES * NODE_F / 8)   // 400000 (16B bf16 chunks)
#define WCHUNKS (OUT_F * IN_F / 8)       // 4096
// per-perm staging: 16 slots x (8 rows x 128 B + 16 B pad) = 16640 B
#define SLOT_E  520                       // bf16 elems per slot (1040 B)
#define BUF_E   (16 * SLOT_E)             // 8320 elems = 16640 B

typedef __bf16 bf16x8 __attribute__((ext_vector_type(8)));
typedef float  f32x4  __attribute__((ext_vector_type(4)));

__device__ __forceinline__ unsigned short f32_to_bf16_rne(unsigned int u) {
    u += 0x7FFFu + ((u >> 16) & 1u);
    return (unsigned short)(u >> 16);
}

// Block-uniform dtype probe (R2-R8 proven: live path is fp32 -> 0).
__device__ __forceinline__ int probe_is_bf16(const void* Xorig) {
    int lane = threadIdx.x & 63;
    unsigned short h = ((const unsigned short*)Xorig)[2 * lane];
    int e = (h >> 7) & 0xFF;
    unsigned long long mm = __ballot(e >= 110 && e <= 140);
    return (__popcll(mm) >= 48) ? 1 : 0;
}

__device__ __forceinline__ void pack8(const uint4* src, uint4* dst, int c) {
    uint4 a = src[2 * c], b = src[2 * c + 1];
    uint4 o;
    o.x = (unsigned int)f32_to_bf16_rne(a.x) | ((unsigned int)f32_to_bf16_rne(a.y) << 16);
    o.y = (unsigned int)f32_to_bf16_rne(a.z) | ((unsigned int)f32_to_bf16_rne(a.w) << 16);
    o.z = (unsigned int)f32_to_bf16_rne(b.x) | ((unsigned int)f32_to_bf16_rne(b.y) << 16);
    o.w = (unsigned int)f32_to_bf16_rne(b.z) | ((unsigned int)f32_to_bf16_rne(b.w) << 16);
    dst[c] = o;
}

// One kernel converts X, W (fp32->bf16, or plain copy if already bf16) and
// bias (->f32) into the workspace. Dtype-agnostic main kernel follows.
__global__ void convert_all(const void* __restrict__ Xv, const void* __restrict__ Wv,
                            const void* __restrict__ Bv, uint4* __restrict__ Xb,
                            uint4* __restrict__ Wb, float* __restrict__ Bf) {
    const int isbf = probe_is_bf16(Xv);
    int c = blockIdx.x * blockDim.x + threadIdx.x;
    if (c < XCHUNKS) {
        if (isbf) Xb[c] = ((const uint4*)Xv)[c];
        else      pack8((const uint4*)Xv, Xb, c);
    } else if (c < XCHUNKS + WCHUNKS) {
        int cw = c - XCHUNKS;
        if (isbf) Wb[cw] = ((const uint4*)Wv)[cw];
        else      pack8((const uint4*)Wv, Wb, cw);
    } else if (c < XCHUNKS + WCHUNKS + OUT_F) {
        int i = c - XCHUNKS - WCHUNKS;
        Bf[i] = isbf ? (float)((const __bf16*)Bv)[i] : ((const float*)Bv)[i];
    }
}

__device__ __forceinline__ float softplus_sh(float x) {
    float t = __expf(-fabsf(x));
    return fmaxf(x, 0.f) + 0.69314718056f * __log2f(1.f + t);
}

// R11: R8 structure (78 us, best) with the gather mechanism SWAPPED.
// Post-mortems R8/R9/R10: all three structures (different LDS-read amp,
// occupancy, barriers) ran the identical global_load_lds gather and all
// landed at ~240 M lines/s/CU (prior 64 B probe: same req rate). Halving
// LDS reads twice gained 0 -> LDS was never binding; the DMA engine's
// per-CU concurrency (~12 insts in flight by Little's law at ~400 ns RTT)
// is. R11: plain per-lane global_load_dwordx4 -> VGPR (same pre-swizzled
// source addresses, 8-lane octet = one 128 B row) + ds_write_b128 to the
// identical linear LDS slots. T14 split, lag-2 pipeline (full p-unroll for
// static Greg/idx parity): iter p issues loads(p+2), ds_writes p+1 (loads
// a full compute phase old -> auto-waitcnt drains only them), computes p,
// one barrier. Plain loads give ~384 lines in flight/CU vs DMA's ~96.
// Everything else byte-identical to R8: wave w owns features 16w..16w+15
// (Wfrag[16], 64 VGPR), chunk XOR swizzle (c ^ lane>>3) + 16 B/slot pad,
// one __syncthreads per perm.
__global__ __launch_bounds__(256, 3)
void lcnn_dma(const void* __restrict__ Xorig, const __bf16* __restrict__ Xb,
              const int* __restrict__ NS, const __bf16* __restrict__ Wb,
              const float* __restrict__ Bf, void* __restrict__ outv)
{
    __shared__ __align__(16) __bf16 Abuf[2][BUF_E];   // 2 x 16640 B

    const int wave = threadIdx.x >> 6;
    const int lane = threadIdx.x & 63;
    const int m    = lane & 15;
    const int quad = lane >> 4;
    const int mk   = m & 7;
    const int mh   = m >> 3;
    const int tile = blockIdx.x;

    // W fragments: B[k][n] with n = 16w+m, k = ks*32 + quad*8 + j
    bf16x8 Wfrag[16];
    #pragma unroll
    for (int ks = 0; ks < 16; ++ks)
        Wfrag[ks] = *(const bf16x8*)(Wb + (size_t)(wave * 16 + m) * IN_F + ks * 32 + quad * 8);

    const float bias = Bf[wave * 16 + m];

    // Slot t = wave*4 + i covers neighbor k = t>>1, sites ((t&1)<<3)+0..7.
    // lane: row-in-slot = lane>>3, source chunk = (lane&7) ^ (lane>>3).
    auto load_idx = [&](int p_, int out[4]) {
        #pragma unroll
        for (int i = 0; i < 4; ++i) {
            int t = wave * 4 + i;
            int s = ((t & 1) << 3) + (lane >> 3);
            int k = t >> 1;
            out[i] = NS[(size_t)(tile * 16 + s) * (N_PERM * N_NEIGH) + p_ * N_NEIGH + k];
        }
    };
    const int csrc = (lane & 7) ^ (lane >> 3);
    auto glo = [&](uint4 G[4], const int idxv[4]) {       // issue 4 row-loads
        #pragma unroll
        for (int i = 0; i < 4; ++i)
            G[i] = *(const uint4*)(Xb + (size_t)idxv[i] * NODE_F + csrc * 8);
    };
    auto stage_write = [&](int buf_, const uint4 G[4]) {  // VGPR -> LDS (linear)
        #pragma unroll
        for (int i = 0; i < 4; ++i) {
            int t = wave * 4 + i;
            *(uint4*)(&Abuf[buf_][t * SLOT_E + (size_t)lane * 8]) = G[i];
        }
    };

    uint4 GA[4], GB[4];
    int idxA[4], idxB[4];

    // Prologue: perm0 -> GA -> buf0; perm1 -> GB (in flight); idxA <- perm2.
    load_idx(0, idxA);
    glo(GA, idxA);
    load_idx(1, idxB);
    stage_write(0, GA);          // auto-waitcnt drains GA loads only
    glo(GB, idxB);
    load_idx(2, idxA);
    __syncthreads();             // buf0 visible to all waves

    f32x4 sum = {0.f, 0.f, 0.f, 0.f};
    #pragma unroll
    for (int p = 0; p < N_PERM; ++p) {
        // Issue loads for p+2 (parity(p+2) == parity(p)) -- deep in flight.
        if (p < N_PERM - 2) { if (p & 1) glo(GB, idxB); else glo(GA, idxA); }
        // Write p+1's rows (loaded a full compute phase ago) into its buffer.
        if (p < N_PERM - 1) {
            if (p & 1) stage_write((p + 1) & 1, GA);
            else       stage_write((p + 1) & 1, GB);
        }
        // Fetch indices for p+3 (parity(p+3) == parity(p+1)).
        if (p < N_PERM - 3) { if (p & 1) load_idx(p + 3, idxA); else load_idx(p + 3, idxB); }

        f32x4 acc = {0.f, 0.f, 0.f, 0.f};
        const __bf16* bb = &Abuf[p & 1][0];
        #pragma unroll
        for (int ks = 0; ks < 16; ++ks) {
            // row r=(ks>>1)*16+m -> slot t=(ks>>1)*2+mh, in-slot row mk;
            // source chunk j=((ks&1)<<2)|quad lives at LDS chunk j^mk.
            int t_r = (ks >> 1) * 2 + mh;
            int j   = ((ks & 1) << 2) | quad;
            bf16x8 afr = *(const bf16x8*)(bb + t_r * SLOT_E + mk * 64 + ((j ^ mk) << 3));
            acc = __builtin_amdgcn_mfma_f32_16x16x32_bf16(afr, Wfrag[ks], acc, 0, 0, 0);
        }
        #pragma unroll
        for (int r = 0; r < 4; ++r) sum[r] += softplus_sh(acc[r] + bias);
        if (p < N_PERM - 1) __syncthreads();   // p+1 buffer staged; this one free
    }

    // C: row = quad*4 + r (site), out feature = 16*wave + m (R8-proven)
    const int isbf = probe_is_bf16(Xorig);
    #pragma unroll
    for (int r = 0; r < 4; ++r) {
        size_t pos = (size_t)(tile * 16 + quad * 4 + r) * OUT_F + wave * 16 + m;
        float v = sum[r] - 12.0f * LN2F;
        if (isbf) ((__bf16*)outv)[pos] = (__bf16)v;
        else      ((float*)outv)[pos]  = v;
    }
}

// Safety net (workspace too small — never seen): direct fp32 compute.
__global__ void lcnn_fallback(const float* __restrict__ X, const int* __restrict__ NS,
                              const float* __restrict__ W, const float* __restrict__ B,
                              float* __restrict__ out) {
    int t = blockIdx.x * blockDim.x + threadIdx.x;
    if (t >= N_SITES * OUT_F) return;
    int sitei = t >> 6, o = t & 63;
    const int* ns = NS + (size_t)sitei * 96;
    float s = 0.f;
    for (int p = 0; p < N_PERM; ++p) {
        float x = B[o];
        for (int n = 0; n < N_NEIGH; ++n) {
            const float* xr = X + (size_t)ns[p * 8 + n] * NODE_F;
            const float* wr = W + (size_t)o * IN_F + n * NODE_F;
            for (int f = 0; f < NODE_F; ++f) x += xr[f] * wr[f];
        }
        s += softplus_sh(x);
    }
    out[t] = s - 12.0f * LN2F;
}

extern "C" void kernel_launch(void* const* d_in, const int* in_sizes, int n_in,
                              void* d_out, int out_size, void* d_ws, size_t ws_size,
                              hipStream_t stream) {
    const void* X  = d_in[0];                // (50000, 64)
    const int*  NS = (const int*)d_in[1];    // (50000, 12, 8) int32
    const void* W  = d_in[2];                // (64, 512)
    const void* B  = d_in[3];                // (64,)

    char* ws = (char*)d_ws;
    __bf16* Xb = (__bf16*)ws;                                     // 6.4 MB
    __bf16* Wb = (__bf16*)(ws + (size_t)XCHUNKS * 16);            // 64 KB
    float*  Bf = (float*)(ws + (size_t)(XCHUNKS + WCHUNKS) * 16); // 256 B
    const bool conv = ws_size >= (size_t)(XCHUNKS + WCHUNKS) * 16 + OUT_F * 4;

    if (conv) {
        int nch = XCHUNKS + WCHUNKS + OUT_F;
        hipLaunchKernelGGL(convert_all, dim3((nch + 255) / 256), dim3(256), 0, stream,
                           X, W, B, (uint4*)Xb, (uint4*)Wb, Bf);
        hipLaunchKernelGGL(lcnn_dma, dim3(N_TILES), dim3(256), 0, stream,
                           X, Xb, NS, Wb, Bf, d_out);
    } else {
        hipLaunchKernelGGL(lcnn_fallback,
                           dim3((N_SITES * OUT_F + 255) / 256), dim3(256), 0, stream,
                           (const float*)X, NS, (const float*)W, (const float*)B,
                           (float*)d_out);
    }
}

// Round 4
// 158.075 us; speedup vs baseline: 2.2276x; 2.2276x over previous
//
#include <hip/hip_runtime.h>
#include <hip/hip_bf16.h>

#define N_SITES 50000
#define N_PERM  12
#define N_NEIGH 8
#define NODE_F  64
#define IN_F    512
#define OUT_F   64
#define N_TILES (N_SITES / 16)   // 3125 exact, one block per tile
#define LN2F    0.69314718055994530942f

#define XCHUNKS (N_SITES * NODE_F / 8)   // 400000 (16B bf16 chunks)
#define WCHUNKS (OUT_F * IN_F / 8)       // 4096
// per-perm staging: 16 slots x (8 rows x 128 B + 16 B pad) = 16640 B
#define SLOT_E  520                       // bf16 elems per slot (1040 B)
#define BUF_E   (16 * SLOT_E)             // 8320 elems = 16640 B

typedef __bf16 bf16x8 __attribute__((ext_vector_type(8)));
typedef float  f32x4  __attribute__((ext_vector_type(4)));

__device__ __forceinline__ unsigned short f32_to_bf16_rne(unsigned int u) {
    u += 0x7FFFu + ((u >> 16) & 1u);
    return (unsigned short)(u >> 16);
}

// Block-uniform dtype probe (R2-R8 proven: live path is fp32 -> 0).
__device__ __forceinline__ int probe_is_bf16(const void* Xorig) {
    int lane = threadIdx.x & 63;
    unsigned short h = ((const unsigned short*)Xorig)[2 * lane];
    int e = (h >> 7) & 0xFF;
    unsigned long long mm = __ballot(e >= 110 && e <= 140);
    return (__popcll(mm) >= 48) ? 1 : 0;
}

__device__ __forceinline__ void pack8(const uint4* src, uint4* dst, int c) {
    uint4 a = src[2 * c], b = src[2 * c + 1];
    uint4 o;
    o.x = (unsigned int)f32_to_bf16_rne(a.x) | ((unsigned int)f32_to_bf16_rne(a.y) << 16);
    o.y = (unsigned int)f32_to_bf16_rne(a.z) | ((unsigned int)f32_to_bf16_rne(a.w) << 16);
    o.z = (unsigned int)f32_to_bf16_rne(b.x) | ((unsigned int)f32_to_bf16_rne(b.y) << 16);
    o.w = (unsigned int)f32_to_bf16_rne(b.z) | ((unsigned int)f32_to_bf16_rne(b.w) << 16);
    dst[c] = o;
}

// One kernel converts X, W (fp32->bf16, or plain copy if already bf16) and
// bias (->f32) into the workspace. Dtype-agnostic main kernel follows.
__global__ void convert_all(const void* __restrict__ Xv, const void* __restrict__ Wv,
                            const void* __restrict__ Bv, uint4* __restrict__ Xb,
                            uint4* __restrict__ Wb, float* __restrict__ Bf) {
    const int isbf = probe_is_bf16(Xv);
    int c = blockIdx.x * blockDim.x + threadIdx.x;
    if (c < XCHUNKS) {
        if (isbf) Xb[c] = ((const uint4*)Xv)[c];
        else      pack8((const uint4*)Xv, Xb, c);
    } else if (c < XCHUNKS + WCHUNKS) {
        int cw = c - XCHUNKS;
        if (isbf) Wb[cw] = ((const uint4*)Wv)[cw];
        else      pack8((const uint4*)Wv, Wb, cw);
    } else if (c < XCHUNKS + WCHUNKS + OUT_F) {
        int i = c - XCHUNKS - WCHUNKS;
        Bf[i] = isbf ? (float)((const __bf16*)Bv)[i] : ((const float*)Bv)[i];
    }
}

__device__ __forceinline__ float softplus_sh(float x) {
    float t = __expf(-fabsf(x));
    return fmaxf(x, 0.f) + 0.69314718056f * __log2f(1.f + t);
}

// R12: valid rerun of R11's experiment. R11's 280 us was NOT the gather --
// it was scratch spill: array-typed lambda params (uint4 G[4]) defeated
// mem2reg; WRITE_SIZE 605 MB == 3125x256x12x64 B of VGPR->scratch round
// trips (rule #20). Side-finding: memory system sustained 4.1 TB/s during
// the spill -> ~2x headroom over R8's consumption. R12 scalarizes ALL
// pipeline state (named uint4 A0..B3, int4 indices, macros -- no
// addressable locals) and otherwise repeats R11's plan: plain per-lane
// global_load_dwordx4 (8-lane octet = one pre-swizzled 128 B row) +
// ds_write_b128 to R8's exact linear LDS slots. Lag-2: iter p issues
// loads(p+2), ds_writes p+1 (loads one full compute phase old -> counted
// vmcnt), computes p, one barrier. Compute/LDS-read side byte-identical
// to R8 (78 us best): wave w owns features 16w..16w+15, chunk XOR swizzle
// (c ^ lane>>3) + 16 B/slot pad.
// Decision: ~55 us -> DMA concurrency was the wall; ~78 us with clean
// counters -> random-128B-gather line-rate roofline (two mechanisms agree).
__global__ __launch_bounds__(256, 3)
void lcnn_dma(const void* __restrict__ Xorig, const __bf16* __restrict__ Xb,
              const int* __restrict__ NS, const __bf16* __restrict__ Wb,
              const float* __restrict__ Bf, void* __restrict__ outv)
{
    __shared__ __align__(16) __bf16 Abuf[2][BUF_E];   // 2 x 16640 B

    const int wave = threadIdx.x >> 6;
    const int lane = threadIdx.x & 63;
    const int m    = lane & 15;
    const int quad = lane >> 4;
    const int mk   = m & 7;
    const int mh   = m >> 3;
    const int tile = blockIdx.x;

    // W fragments: B[k][n] with n = 16w+m, k = ks*32 + quad*8 + j
    bf16x8 Wfrag[16];
    #pragma unroll
    for (int ks = 0; ks < 16; ++ks)
        Wfrag[ks] = *(const bf16x8*)(Wb + (size_t)(wave * 16 + m) * IN_F + ks * 32 + quad * 8);

    const float bias = Bf[wave * 16 + m];

    // Slot t = wave*4 + i: neighbor k = wave*2 + (i>>1), site s = ((i&1)<<3) + (lane>>3).
    const int srow = lane >> 3;
    const int csrc = (lane & 7) ^ srow;               // pre-swizzled source chunk
    const int* ns0 = NS + (size_t)(tile * 16 + srow)     * (N_PERM * N_NEIGH) + wave * 2;
    const int* ns1 = NS + (size_t)(tile * 16 + srow + 8) * (N_PERM * N_NEIGH) + wave * 2;

#define LIDX(iv, p_) do {                                                     \
        (iv).x = ns0[(p_) * N_NEIGH];     (iv).y = ns1[(p_) * N_NEIGH];       \
        (iv).z = ns0[(p_) * N_NEIGH + 1]; (iv).w = ns1[(p_) * N_NEIGH + 1];   \
    } while (0)

#define GLO(g0, g1, g2, g3, iv) do {                                          \
        g0 = *(const uint4*)(Xb + (size_t)(iv).x * NODE_F + csrc * 8);        \
        g1 = *(const uint4*)(Xb + (size_t)(iv).y * NODE_F + csrc * 8);        \
        g2 = *(const uint4*)(Xb + (size_t)(iv).z * NODE_F + csrc * 8);        \
        g3 = *(const uint4*)(Xb + (size_t)(iv).w * NODE_F + csrc * 8);        \
    } while (0)

#define STW(buf_, g0, g1, g2, g3) do {                                        \
        *(uint4*)(&Abuf[buf_][(wave * 4 + 0) * SLOT_E + lane * 8]) = g0;      \
        *(uint4*)(&Abuf[buf_][(wave * 4 + 1) * SLOT_E + lane * 8]) = g1;      \
        *(uint4*)(&Abuf[buf_][(wave * 4 + 2) * SLOT_E + lane * 8]) = g2;      \
        *(uint4*)(&Abuf[buf_][(wave * 4 + 3) * SLOT_E + lane * 8]) = g3;      \
    } while (0)

    uint4 A0, A1, A2, A3, B0, B1, B2, B3;
    int4  iA, iB;

    // Prologue: perm0 -> A -> buf0; perm1 loads in flight in B; iA <- perm2.
    LIDX(iA, 0);
    GLO(A0, A1, A2, A3, iA);
    LIDX(iB, 1);
    STW(0, A0, A1, A2, A3);      // compiler waits on A loads only
    GLO(B0, B1, B2, B3, iB);
    LIDX(iA, 2);
    __syncthreads();             // buf0 visible to all waves

    f32x4 sum = {0.f, 0.f, 0.f, 0.f};
    #pragma unroll
    for (int p = 0; p < N_PERM; ++p) {
        // Issue loads for p+2 (same parity as p) -- deep in flight.
        if (p < N_PERM - 2) {
            if (p & 1) GLO(B0, B1, B2, B3, iB);
            else       GLO(A0, A1, A2, A3, iA);
        }
        // Write p+1's rows (loaded one full compute phase ago).
        if (p < N_PERM - 1) {
            if (p & 1) STW((p + 1) & 1, A0, A1, A2, A3);
            else       STW((p + 1) & 1, B0, B1, B2, B3);
        }
        // Indices for p+3 (same parity as p+1).
        if (p < N_PERM - 3) {
            if (p & 1) LIDX(iA, p + 3);
            else       LIDX(iB, p + 3);
        }

        f32x4 acc = {0.f, 0.f, 0.f, 0.f};
        const __bf16* bb = &Abuf[p & 1][0];
        #pragma unroll
        for (int ks = 0; ks < 16; ++ks) {
            // row r=(ks>>1)*16+m -> slot t=(ks>>1)*2+mh, in-slot row mk;
            // source chunk j=((ks&1)<<2)|quad lives at LDS chunk j^mk.
            int t_r = (ks >> 1) * 2 + mh;
            int j   = ((ks & 1) << 2) | quad;
            bf16x8 afr = *(const bf16x8*)(bb + t_r * SLOT_E + mk * 64 + ((j ^ mk) << 3));
            acc = __builtin_amdgcn_mfma_f32_16x16x32_bf16(afr, Wfrag[ks], acc, 0, 0, 0);
        }
        #pragma unroll
        for (int r = 0; r < 4; ++r) sum[r] += softplus_sh(acc[r] + bias);
        if (p < N_PERM - 1) __syncthreads();   // p+1 buffer staged; this one free
    }

#undef LIDX
#undef GLO
#undef STW

    // C: row = quad*4 + r (site), out feature = 16*wave + m (R8-proven)
    const int isbf = probe_is_bf16(Xorig);
    #pragma unroll
    for (int r = 0; r < 4; ++r) {
        size_t pos = (size_t)(tile * 16 + quad * 4 + r) * OUT_F + wave * 16 + m;
        float v = sum[r] - 12.0f * LN2F;
        if (isbf) ((__bf16*)outv)[pos] = (__bf16)v;
        else      ((float*)outv)[pos]  = v;
    }
}

// Safety net (workspace too small — never seen): direct fp32 compute.
__global__ void lcnn_fallback(const float* __restrict__ X, const int* __restrict__ NS,
                              const float* __restrict__ W, const float* __restrict__ B,
                              float* __restrict__ out) {
    int t = blockIdx.x * blockDim.x + threadIdx.x;
    if (t >= N_SITES * OUT_F) return;
    int sitei = t >> 6, o = t & 63;
    const int* ns = NS + (size_t)sitei * 96;
    float s = 0.f;
    for (int p = 0; p < N_PERM; ++p) {
        float x = B[o];
        for (int n = 0; n < N_NEIGH; ++n) {
            const float* xr = X + (size_t)ns[p * 8 + n] * NODE_F;
            const float* wr = W + (size_t)o * IN_F + n * NODE_F;
            for (int f = 0; f < NODE_F; ++f) x += xr[f] * wr[f];
        }
        s += softplus_sh(x);
    }
    out[t] = s - 12.0f * LN2F;
}

extern "C" void kernel_launch(void* const* d_in, const int* in_sizes, int n_in,
                              void* d_out, int out_size, void* d_ws, size_t ws_size,
                              hipStream_t stream) {
    const void* X  = d_in[0];                // (50000, 64)
    const int*  NS = (const int*)d_in[1];    // (50000, 12, 8) int32
    const void* W  = d_in[2];                // (64, 512)
    const void* B  = d_in[3];                // (64,)

    char* ws = (char*)d_ws;
    __bf16* Xb = (__bf16*)ws;                                     // 6.4 MB
    __bf16* Wb = (__bf16*)(ws + (size_t)XCHUNKS * 16);            // 64 KB
    float*  Bf = (float*)(ws + (size_t)(XCHUNKS + WCHUNKS) * 16); // 256 B
    const bool conv = ws_size >= (size_t)(XCHUNKS + WCHUNKS) * 16 + OUT_F * 4;

    if (conv) {
        int nch = XCHUNKS + WCHUNKS + OUT_F;
        hipLaunchKernelGGL(convert_all, dim3((nch + 255) / 256), dim3(256), 0, stream,
                           X, W, B, (uint4*)Xb, (uint4*)Wb, Bf);
        hipLaunchKernelGGL(lcnn_dma, dim3(N_TILES), dim3(256), 0, stream,
                           X, Xb, NS, Wb, Bf, d_out);
    } else {
        hipLaunchKernelGGL(lcnn_fallback,
                           dim3((N_SITES * OUT_F + 255) / 256), dim3(256), 0, stream,
                           (const float*)X, NS, (const float*)W, (const float*)B,
                           (float*)d_out);
    }
}

// Round 5
// 142.251 us; speedup vs baseline: 2.4754x; 1.1112x over previous
//
#include <hip/hip_runtime.h>
#include <hip/hip_bf16.h>

#define N_SITES 50000
#define N_PERM  12
#define N_NEIGH 8
#define NODE_F  64
#define IN_F    512
#define OUT_F   64
#define N_TILES (N_SITES / 16)   // 3125 exact, one block per tile
#define LN2F    0.69314718055994530942f

#define XCHUNKS (N_SITES * NODE_F / 8)   // 400000 (16B bf16 chunks)
#define WCHUNKS (OUT_F * IN_F / 8)       // 4096
// per-perm staging: 16 slots x (8 rows x 128 B + 16 B pad) = 16640 B
#define SLOT_E  520                       // bf16 elems per slot (1040 B)
#define BUF_E   (16 * SLOT_E)             // 8320 elems = 16640 B

typedef __bf16 bf16x8 __attribute__((ext_vector_type(8)));
typedef float  f32x4  __attribute__((ext_vector_type(4)));

__device__ __forceinline__ unsigned short f32_to_bf16_rne(unsigned int u) {
    u += 0x7FFFu + ((u >> 16) & 1u);
    return (unsigned short)(u >> 16);
}

// Block-uniform dtype probe (R2-R8 proven: live path is fp32 -> 0).
__device__ __forceinline__ int probe_is_bf16(const void* Xorig) {
    int lane = threadIdx.x & 63;
    unsigned short h = ((const unsigned short*)Xorig)[2 * lane];
    int e = (h >> 7) & 0xFF;
    unsigned long long mm = __ballot(e >= 110 && e <= 140);
    return (__popcll(mm) >= 48) ? 1 : 0;
}

__device__ __forceinline__ void pack8(const uint4* src, uint4* dst, int c) {
    uint4 a = src[2 * c], b = src[2 * c + 1];
    uint4 o;
    o.x = (unsigned int)f32_to_bf16_rne(a.x) | ((unsigned int)f32_to_bf16_rne(a.y) << 16);
    o.y = (unsigned int)f32_to_bf16_rne(a.z) | ((unsigned int)f32_to_bf16_rne(a.w) << 16);
    o.z = (unsigned int)f32_to_bf16_rne(b.x) | ((unsigned int)f32_to_bf16_rne(b.y) << 16);
    o.w = (unsigned int)f32_to_bf16_rne(b.z) | ((unsigned int)f32_to_bf16_rne(b.w) << 16);
    dst[c] = o;
}

// One kernel converts X, W (fp32->bf16, or plain copy if already bf16) and
// bias (->f32) into the workspace. Dtype-agnostic main kernel follows.
__global__ void convert_all(const void* __restrict__ Xv, const void* __restrict__ Wv,
                            const void* __restrict__ Bv, uint4* __restrict__ Xb,
                            uint4* __restrict__ Wb, float* __restrict__ Bf) {
    const int isbf = probe_is_bf16(Xv);
    int c = blockIdx.x * blockDim.x + threadIdx.x;
    if (c < XCHUNKS) {
        if (isbf) Xb[c] = ((const uint4*)Xv)[c];
        else      pack8((const uint4*)Xv, Xb, c);
    } else if (c < XCHUNKS + WCHUNKS) {
        int cw = c - XCHUNKS;
        if (isbf) Wb[cw] = ((const uint4*)Wv)[cw];
        else      pack8((const uint4*)Wv, Wb, cw);
    } else if (c < XCHUNKS + WCHUNKS + OUT_F) {
        int i = c - XCHUNKS - WCHUNKS;
        Bf[i] = isbf ? (float)((const __bf16*)Bv)[i] : ((const float*)Bv)[i];
    }
}

__device__ __forceinline__ float softplus_sh(float x) {
    float t = __expf(-fabsf(x));
    return fmaxf(x, 0.f) + 0.69314718056f * __log2f(1.f + t);
}

__device__ __forceinline__ void async16(const __bf16* g, __bf16* l) {
    __builtin_amdgcn_global_load_lds(
        (const __attribute__((address_space(1))) unsigned int*)g,
        (__attribute__((address_space(3))) unsigned int*)l, 16, 0, 0);
}

// R13: R8 (78 us best) + T3/T4 counted-vmcnt deep pipeline.
// Post-mortems: R9/R10 (LDS-amp cuts) gained 0 -> LDS not binding. R12
// (clean plain-load gather) = 92 us -> global_load_lds is the BETTER
// mechanism; no DMA-engine cap. Remaining theory: R8 is burst-drain bound
// -- its per-perm __syncthreads is a vmcnt(0) drain, so per-wave gather
// concurrency sawtooths 4->0 every perm and the CU parks on the slowest
// of 128 lines (23% HBM-miss ~900cyc). R13: 3 buffers, lag-2 stage, and
// s_waitcnt vmcnt(4) at the barrier (drains p+1's 4 DMAs ONLY; p+2's 4
// stay in flight across the barrier -- AITER/never-drain-to-0 pattern).
// All 12 perms' indices preloaded to registers once (int4 idx[12],
// constant-indexed post-unroll) so the vmcnt stream is pure stage-DMAs.
// Everything else byte-identical to R8: wave w owns features 16w..16w+15,
// 16 DMA slots/perm, 8-lane octet = one 128 B row, chunk XOR swizzle
// (c ^ lane>>3) + 16 B/slot pad. LDS 49.9 KB -> 3 blocks/CU (12 waves,
// same as R8's measured occupancy).
// Decision: ~55-65 us -> drain was the wall; ~78 us clean -> three
// structures agree at ~62 G lines/s = random-gather service roofline.

#define BARX(N) do {                                                          \
        asm volatile("s_waitcnt vmcnt(" #N ") lgkmcnt(0)" ::: "memory");      \
        __builtin_amdgcn_s_barrier();                                         \
        asm volatile("" ::: "memory");                                        \
    } while (0)

__global__ __launch_bounds__(256, 3)
void lcnn_dma(const void* __restrict__ Xorig, const __bf16* __restrict__ Xb,
              const int* __restrict__ NS, const __bf16* __restrict__ Wb,
              const float* __restrict__ Bf, void* __restrict__ outv)
{
    __shared__ __align__(16) __bf16 Abuf[3][BUF_E];   // 3 x 16640 B = 49.9 KB

    const int wave = threadIdx.x >> 6;
    const int lane = threadIdx.x & 63;
    const int m    = lane & 15;
    const int quad = lane >> 4;
    const int mk   = m & 7;
    const int mh   = m >> 3;
    const int tile = blockIdx.x;

    // W fragments: B[k][n] with n = 16w+m, k = ks*32 + quad*8 + j
    bf16x8 Wfrag[16];
    #pragma unroll
    for (int ks = 0; ks < 16; ++ks)
        Wfrag[ks] = *(const bf16x8*)(Wb + (size_t)(wave * 16 + m) * IN_F + ks * 32 + quad * 8);

    const float bias = Bf[wave * 16 + m];

    // Slot t = wave*4 + i: neighbor k = wave*2 + (i>>1), site ((i&1)<<3)+srow.
    // lane: row-in-slot = srow = lane>>3, source chunk = (lane&7) ^ srow.
    const int srow = lane >> 3;
    const int csrc = (lane & 7) ^ srow;
    const int* ns0 = NS + (size_t)(tile * 16 + srow)     * (N_PERM * N_NEIGH) + wave * 2;
    const int* ns1 = NS + (size_t)(tile * 16 + srow + 8) * (N_PERM * N_NEIGH) + wave * 2;

    // Preload ALL perms' indices (R12-proven slot mapping). Constant-indexed
    // after full unroll -> stays in VGPRs (48); keeps vmcnt stream pure.
    int4 idx[N_PERM];
    #pragma unroll
    for (int p = 0; p < N_PERM; ++p) {
        idx[p].x = ns0[p * N_NEIGH];     idx[p].y = ns1[p * N_NEIGH];
        idx[p].z = ns0[p * N_NEIGH + 1]; idx[p].w = ns1[p * N_NEIGH + 1];
    }

    auto stagep = [&](int bslot, int4 iv) {
        async16(Xb + (size_t)iv.x * NODE_F + csrc * 8, &Abuf[bslot][(wave * 4 + 0) * SLOT_E]);
        async16(Xb + (size_t)iv.y * NODE_F + csrc * 8, &Abuf[bslot][(wave * 4 + 1) * SLOT_E]);
        async16(Xb + (size_t)iv.z * NODE_F + csrc * 8, &Abuf[bslot][(wave * 4 + 2) * SLOT_E]);
        async16(Xb + (size_t)iv.w * NODE_F + csrc * 8, &Abuf[bslot][(wave * 4 + 3) * SLOT_E]);
    };

    // Prologue: two perms in flight, wait for the first only.
    stagep(0, idx[0]);
    stagep(1, idx[1]);
    BARX(4);                      // perm0 staged; perm1's 4 DMAs still flying

    f32x4 sum = {0.f, 0.f, 0.f, 0.f};
    #pragma unroll
    for (int p = 0; p < N_PERM; ++p) {
        if (p < N_PERM - 2) stagep((p + 2) % 3, idx[p + 2]);

        f32x4 acc = {0.f, 0.f, 0.f, 0.f};
        const __bf16* bb = &Abuf[p % 3][0];
        #pragma unroll
        for (int ks = 0; ks < 16; ++ks) {
            // row r=(ks>>1)*16+m -> slot t=(ks>>1)*2+mh, in-slot row mk;
            // source chunk j=((ks&1)<<2)|quad lives at LDS chunk j^mk.
            int t_r = (ks >> 1) * 2 + mh;
            int j   = ((ks & 1) << 2) | quad;
            bf16x8 afr = *(const bf16x8*)(bb + t_r * SLOT_E + mk * 64 + ((j ^ mk) << 3));
            acc = __builtin_amdgcn_mfma_f32_16x16x32_bf16(afr, Wfrag[ks], acc, 0, 0, 0);
        }
        #pragma unroll
        for (int r = 0; r < 4; ++r) sum[r] += softplus_sh(acc[r] + bias);

        // Counted drain: p+1's stage complete, p+2's stays in flight.
        if (p < N_PERM - 2)      BARX(4);
        else if (p < N_PERM - 1) BARX(0);
    }

    // C: row = quad*4 + r (site), out feature = 16*wave + m (R8-proven)
    const int isbf = probe_is_bf16(Xorig);
    #pragma unroll
    for (int r = 0; r < 4; ++r) {
        size_t pos = (size_t)(tile * 16 + quad * 4 + r) * OUT_F + wave * 16 + m;
        float v = sum[r] - 12.0f * LN2F;
        if (isbf) ((__bf16*)outv)[pos] = (__bf16)v;
        else      ((float*)outv)[pos]  = v;
    }
}

// Safety net (workspace too small — never seen): direct fp32 compute.
__global__ void lcnn_fallback(const float* __restrict__ X, const int* __restrict__ NS,
                              const float* __restrict__ W, const float* __restrict__ B,
                              float* __restrict__ out) {
    int t = blockIdx.x * blockDim.x + threadIdx.x;
    if (t >= N_SITES * OUT_F) return;
    int sitei = t >> 6, o = t & 63;
    const int* ns = NS + (size_t)sitei * 96;
    float s = 0.f;
    for (int p = 0; p < N_PERM; ++p) {
        float x = B[o];
        for (int n = 0; n < N_NEIGH; ++n) {
            const float* xr = X + (size_t)ns[p * 8 + n] * NODE_F;
            const float* wr = W + (size_t)o * IN_F + n * NODE_F;
            for (int f = 0; f < NODE_F; ++f) x += xr[f] * wr[f];
        }
        s += softplus_sh(x);
    }
    out[t] = s - 12.0f * LN2F;
}

extern "C" void kernel_launch(void* const* d_in, const int* in_sizes, int n_in,
                              void* d_out, int out_size, void* d_ws, size_t ws_size,
                              hipStream_t stream) {
    const void* X  = d_in[0];                // (50000, 64)
    const int*  NS = (const int*)d_in[1];    // (50000, 12, 8) int32
    const void* W  = d_in[2];                // (64, 512)
    const void* B  = d_in[3];                // (64,)

    char* ws = (char*)d_ws;
    __bf16* Xb = (__bf16*)ws;                                     // 6.4 MB
    __bf16* Wb = (__bf16*)(ws + (size_t)XCHUNKS * 16);            // 64 KB
    float*  Bf = (float*)(ws + (size_t)(XCHUNKS + WCHUNKS) * 16); // 256 B
    const bool conv = ws_size >= (size_t)(XCHUNKS + WCHUNKS) * 16 + OUT_F * 4;

    if (conv) {
        int nch = XCHUNKS + WCHUNKS + OUT_F;
        hipLaunchKernelGGL(convert_all, dim3((nch + 255) / 256), dim3(256), 0, stream,
                           X, W, B, (uint4*)Xb, (uint4*)Wb, Bf);
        hipLaunchKernelGGL(lcnn_dma, dim3(N_TILES), dim3(256), 0, stream,
                           X, Xb, NS, Wb, Bf, d_out);
    } else {
        hipLaunchKernelGGL(lcnn_fallback,
                           dim3((N_SITES * OUT_F + 255) / 256), dim3(256), 0, stream,
                           (const float*)X, NS, (const float*)W, (const float*)B,
                           (float*)d_out);
    }
}